// Round 18
// baseline (338.390 us; speedup 1.0000x reference)
//
#include <hip/hip_runtime.h>
#include <hip/hip_fp16.h>
#include <stdint.h>

typedef __attribute__((ext_vector_type(4))) int int32x4;
typedef __attribute__((ext_vector_type(4))) float float32x4;

#define TOKENS 8192
#define IN_F   4096
#define OUT_F  4096
#define BM 256
#define BN 256
#define BK 128              // int8 per K-tile = 128 B rows
#define NT (IN_F / BK)      // 32 K-tiles
#define ESTR 260            // epilogue LDS row stride (f32): 2-way bank alias = free

#define AS1 __attribute__((address_space(1)))
#define AS3 __attribute__((address_space(3)))

// ------- fused pack: int32->int8 for x and w, plus bias tuple-output -------
__global__ __launch_bounds__(256)
void pack_all_kernel(const int* __restrict__ x32, const int* __restrict__ w32,
                     const float* __restrict__ bias,
                     uint32_t* __restrict__ x8, uint32_t* __restrict__ w8,
                     float* __restrict__ bias_out)
{
    const int gid = blockIdx.x * 256 + threadIdx.x;
    if (gid < OUT_F / 4) {
        float32x4 b4 = __builtin_nontemporal_load((const float32x4*)bias + gid);
        __builtin_nontemporal_store(b4, (float32x4*)bias_out + gid);
    }

    const int nx4 = TOKENS * IN_F / 4;
    const int nw4 = OUT_F * IN_F / 4;
    for (int i = gid; i < nx4 + nw4; i += gridDim.x * 256) {
        const int* s; uint32_t* d; int j;
        if (i < nx4) { s = x32; d = x8; j = i; }
        else         { s = w32; d = w8; j = i - nx4; }
        int32x4 v = __builtin_nontemporal_load((const int32x4*)s + j);
        d[j] = (uint32_t)(v[0] & 0xff) | ((uint32_t)(v[1] & 0xff) << 8) |
               ((uint32_t)(v[2] & 0xff) << 16) | ((uint32_t)v[3] << 24);
    }
}

// ---- 256x256 i8 GEMM: A via LDS (64 KB dbuf), B global->register ----------
// 512 threads = 8 waves (4 wqm x 2 wqn), wave-tile 64 rows x 128 cols.
// LESSON (r16/r17): LDS-DMA (global_load_lds) and VMEM-to-VGPR completions
// are NOT reliably ordered in vmcnt -> never infer an LDS-DMA drain from a
// register-dep wait on younger regular loads. Every tile therefore ends with
// an unconditional s_waitcnt vmcnt(0) (drains both classes) + s_barrier.
// All drained ops were issued this tile with >=1300 cy of MFMA cover.
__global__ __launch_bounds__(512, 2)
void w8a8_gemm_kernel(const int8_t* __restrict__ x,
                      const int8_t* __restrict__ wq,
                      const float* __restrict__ scale,
                      const float* __restrict__ bias,
                      float* __restrict__ out)
{
    __shared__ int8_t smem[65536];             // A dbuf [2][2][128][128B]; epilogue reuse
    int8_t* lA = smem;

    const int tid = threadIdx.x;
    const int wv  = tid >> 6;
    const int l   = tid & 63;
    const int wqm = wv >> 1;               // 0..3  (32-row strip within 128-row half)
    const int wqn = wv & 1;                // 0..1  (64-col strip within 128-col half)

    // XCD-chunked bijective swizzle (r10-proven): 512 blocks = 8 XCDs x (8bn x 8bm)
    const int xc  = blockIdx.x & 7;
    const int idx = blockIdx.x >> 3;
    const int bn  = (xc & 1) * 8 + (idx & 7);    // 0..15
    const int bm  = (xc >> 1) * 8 + (idx >> 3);  // 0..31

    const int8_t* baseA = x + (size_t)bm * BM * IN_F;

    // A staging: T2 swizzle via pre-swizzled global source (rule 21)
    const int seg0 = wv * 2, seg1 = wv * 2 + 1;   // 16 segs x 8 rows per half
    const int r8   = l >> 3;
    const int swc  = (((l & 7) ^ r8) << 4);
    const int8_t* pA0 = baseA + (size_t)(seg0 * 8 + r8) * IN_F + swc;
    const int8_t* pA1 = baseA + (size_t)(seg1 * 8 + r8) * IN_F + swc;

    // fragment read addressing (A from LDS)
    const int fr  = l & 15;
    const int xk  = (l & 7) << 4;
    const int cb0 = (l >> 4) << 4;

    // B global per-lane base: row = bn*256 + wqn*64 + (l&15); k-chunk (l>>4)*16.
    // One dwordx4 across the wave = 16 x 64B lines, each line feeding 4 lanes;
    // lines shared by the 4 wqm-waves -> L1 hits.
    const int8_t* pB = wq + (size_t)(bn * 256 + wqn * 64 + fr) * IN_F + ((l >> 4) << 4);

    int32x4 acc[2][2][2][4];
#pragma unroll
    for (int a0i = 0; a0i < 2; ++a0i)
#pragma unroll
        for (int a1i = 0; a1i < 2; ++a1i)
#pragma unroll
            for (int a2i = 0; a2i < 2; ++a2i)
#pragma unroll
                for (int a3i = 0; a3i < 4; ++a3i)
                    acc[a0i][a1i][a2i][a3i] = (int32x4){0, 0, 0, 0};

    int32x4 aF[2][2][2];   // [MH][mi][ks], 32 VGPR
    int32x4 bK0[2][4];     // B frags ks=0 [NH][ni], 32 VGPR
    int32x4 bK1[2][4];     // B frags ks=1

    auto stage_A = [&](int t) {                // 4 x global_load_lds, 32 KB
        int8_t* db = lA + ((t & 1) << 15);
        const size_t co = (size_t)t * BK;
        __builtin_amdgcn_global_load_lds((const AS1 void*)(pA0 + co),
                                         (AS3 void*)(db + seg0 * 1024), 16, 0, 0);
        __builtin_amdgcn_global_load_lds((const AS1 void*)(pA1 + co),
                                         (AS3 void*)(db + seg1 * 1024), 16, 0, 0);
        __builtin_amdgcn_global_load_lds((const AS1 void*)(pA0 + 128 * IN_F + co),
                                         (AS3 void*)(db + 16384 + seg0 * 1024), 16, 0, 0);
        __builtin_amdgcn_global_load_lds((const AS1 void*)(pA1 + 128 * IN_F + co),
                                         (AS3 void*)(db + 16384 + seg1 * 1024), 16, 0, 0);
    };

#define LDA_ALL(LABP)                                                                  \
    do {                                                                               \
        _Pragma("unroll") for (int MH = 0; MH < 2; ++MH)                               \
        _Pragma("unroll") for (int mi = 0; mi < 2; ++mi)                               \
        _Pragma("unroll") for (int ks = 0; ks < 2; ++ks)                               \
            aF[MH][mi][ks] = *(const int32x4*)&(LABP)[(MH << 14) +                     \
                (wqm * 32 + mi * 16 + fr) * 128 + (((ks * 64) + cb0) ^ xk)];           \
    } while (0)

#define LDBG(DST, T, KS)                                                               \
    do {                                                                               \
        _Pragma("unroll") for (int NH = 0; NH < 2; ++NH)                               \
        _Pragma("unroll") for (int ni = 0; ni < 4; ++ni)                               \
            DST[NH][ni] = *(const int32x4*)(pB +                                       \
                (size_t)(NH * 128 + ni * 16) * IN_F + (T) * 128 + (KS) * 64);          \
    } while (0)

#define MMAK(KS, BSET)                                                                 \
    do {                                                                               \
        _Pragma("unroll") for (int MH = 0; MH < 2; ++MH)                               \
        _Pragma("unroll") for (int NH = 0; NH < 2; ++NH)                               \
        _Pragma("unroll") for (int mi = 0; mi < 2; ++mi)                               \
        _Pragma("unroll") for (int ni = 0; ni < 4; ++ni)                               \
            acc[MH][NH][mi][ni] = __builtin_amdgcn_mfma_i32_16x16x64_i8(               \
                aF[MH][mi][KS], BSET[NH][ni], acc[MH][NH][mi][ni], 0, 0, 0);           \
    } while (0)

    // ---- prologue: A(0) staged + B(0,ks0); unconditional drain ----
    stage_A(0);
    LDBG(bK0, 0, 0);
    asm volatile("s_waitcnt vmcnt(0)" ::: "memory");
    __builtin_amdgcn_s_barrier();

    // ---- main loop: explicit class-blind drain each tile ----
    for (int t = 0; t < NT; ++t) {
        const int8_t* lAb = lA + ((t & 1) << 15);

        LDA_ALL(lAb);                          // 8 ds_read_b128
        if (t + 1 < NT) stage_A(t + 1);        // 4 gload_lds -> other parity
        LDBG(bK1, t, 1);                       // 16 global loads (covered by MMAK(0))

        MMAK(0, bK0);                          // 32 MFMA (bK0 from last tile / prologue)
        if (t + 1 < NT) LDBG(bK0, t + 1, 0);   // refill (covered by MMAK(1))
        MMAK(1, bK1);                          // 32 MFMA

        asm volatile("s_waitcnt vmcnt(0)" ::: "memory");   // drains BOTH vmem classes
        __builtin_amdgcn_s_barrier();          // A(t+1) visible cross-wave
    }

    // ---- epilogue: LDS-staged coalesced float4 nt stores (32-row chunks) ----
    __syncthreads();
    int* eL = (int*)smem;
    const int c4   = tid & 63;          // float4 col index within 256-col block
    const int rowt = tid >> 6;          // 0..7
    const float32x4 sc4 = ((const float32x4*)scale)[bn * 64 + c4];
    const float32x4 bf4 = ((const float32x4*)bias )[bn * 64 + c4];
    const __half bh[4] = { __float2half(bf4[0]), __float2half(bf4[1]),
                           __float2half(bf4[2]), __float2half(bf4[3]) };
    const int r0 = (l >> 4) << 2;

    for (int c = 0; c < 8; ++c) {              // 8 chunks of 32 output rows
        if (wqm == (c & 3)) {
            const int MH = c >> 2;
#pragma unroll
            for (int NH = 0; NH < 2; ++NH)
#pragma unroll
                for (int mi = 0; mi < 2; ++mi)
#pragma unroll
                    for (int ni = 0; ni < 4; ++ni)
#pragma unroll
                        for (int r = 0; r < 4; ++r)
                            eL[(mi * 16 + r0 + r) * ESTR +
                               NH * 128 + wqn * 64 + ni * 16 + fr] = acc[MH][NH][mi][ni][r];
        }
        __syncthreads();
#pragma unroll
        for (int p = 0; p < 4; ++p) {          // 32 rows, 8 per pass
            const int rl = p * 8 + rowt;
            int32x4 v = *(const int32x4*)&eL[rl * ESTR + c4 * 4];
            float32x4 o;
#pragma unroll
            for (int j = 0; j < 4; ++j) {
                __half h = __float2half((float)v[j] * sc4[j]);
                o[j] = __half2float(__hadd(h, bh[j]));
            }
            const size_t rowg = (size_t)(bm * 256 + c * 32 + rl);
            __builtin_nontemporal_store(o, (float32x4*)out + rowg * (OUT_F / 4) + bn * 64 + c4);
        }
        __syncthreads();   // copy-out done before next chunk overwrites
    }
#undef LDA_ALL
#undef LDBG
#undef MMAK
}

extern "C" void kernel_launch(void* const* d_in, const int* in_sizes, int n_in,
                              void* d_out, int out_size, void* d_ws, size_t ws_size,
                              hipStream_t stream)
{
    const int*   x32   = (const int*)d_in[0];
    const int*   w32   = (const int*)d_in[1];
    const float* scale = (const float*)d_in[2];
    const float* bias  = (const float*)d_in[3];
    float* out = (float*)d_out;

    int8_t* x8 = (int8_t*)d_ws;
    int8_t* w8 = x8 + (size_t)TOKENS * IN_F;

    pack_all_kernel<<<3072, 256, 0, stream>>>(x32, w32, bias, (uint32_t*)x8, (uint32_t*)w8,
                                              out + (size_t)TOKENS * OUT_F);

    w8a8_gemm_kernel<<<512, 512, 0, stream>>>(x8, w8, scale, bias, out);
}

// Round 19
// 210.790 us; speedup vs baseline: 1.6053x; 1.6053x over previous
//
#include <hip/hip_runtime.h>
#include <hip/hip_fp16.h>
#include <stdint.h>

typedef __attribute__((ext_vector_type(4)))  int int32x4;
typedef __attribute__((ext_vector_type(16))) int int32x16;
typedef __attribute__((ext_vector_type(4)))  float float32x4;

#define TOKENS 8192
#define IN_F   4096
#define OUT_F  4096
#define BM 256
#define BN 256
#define BK 128              // int8 per K-tile = 128 B rows
#define NT (IN_F / BK)      // 32 K-tiles
#define ESTR 260            // epilogue LDS row stride (f32): 2-way bank alias = free

#define AS1 __attribute__((address_space(1)))
#define AS3 __attribute__((address_space(3)))

// ------- fused pack: int32->int8 for x and w, plus bias tuple-output -------
__global__ __launch_bounds__(256)
void pack_all_kernel(const int* __restrict__ x32, const int* __restrict__ w32,
                     const float* __restrict__ bias,
                     uint32_t* __restrict__ x8, uint32_t* __restrict__ w8,
                     float* __restrict__ bias_out)
{
    const int gid = blockIdx.x * 256 + threadIdx.x;
    if (gid < OUT_F / 4) {
        float32x4 b4 = __builtin_nontemporal_load((const float32x4*)bias + gid);
        __builtin_nontemporal_store(b4, (float32x4*)bias_out + gid);
    }

    const int nx4 = TOKENS * IN_F / 4;
    const int nw4 = OUT_F * IN_F / 4;
    for (int i = gid; i < nx4 + nw4; i += gridDim.x * 256) {
        const int* s; uint32_t* d; int j;
        if (i < nx4) { s = x32; d = x8; j = i; }
        else         { s = w32; d = w8; j = i - nx4; }
        int32x4 v = __builtin_nontemporal_load((const int32x4*)s + j);
        d[j] = (uint32_t)(v[0] & 0xff) | ((uint32_t)(v[1] & 0xff) << 8) |
               ((uint32_t)(v[2] & 0xff) << 16) | ((uint32_t)v[3] << 24);
    }
}

// ---- 256x256 i8 GEMM: r12 structure + 32x32x32 MFMA shape -----------------
// 512 threads = 8 waves (4 wqm x 2 wqn), wave-tile 64 rows x 128 cols.
// Per tile: 24 ds_read_b128 (8 A + 16 B frags) + 8 gload_lds (tile t+1) +
// 32 x mfma_i32_32x32x32_i8 (half the instr count of 16x16x64 for the same
// work; ubench +12% ceiling) + vmcnt(0) + ONE barrier.
// A-frag: row = l&31, k-half = l>>5 (analog of the verified 16x16 mapping;
// A/B use the same k-map so any k-permutation cancels in the dot product).
// C/D (verified m74/m101): col = lane&31, row = (reg&3)+8*(reg>>2)+4*(lane>>5).
__global__ __launch_bounds__(512, 2)
void w8a8_gemm_kernel(const int8_t* __restrict__ x,
                      const int8_t* __restrict__ wq,
                      const float* __restrict__ scale,
                      const float* __restrict__ bias,
                      float* __restrict__ out)
{
    __shared__ int8_t smem[131072];            // staging: lA | lB ; epilogue reuse
    int8_t* lA = smem;                         // [buf][half][128][128B] 64 KB
    int8_t* lB = smem + 65536;                 // 64 KB

    const int tid = threadIdx.x;
    const int wv  = tid >> 6;
    const int l   = tid & 63;
    const int wqm = wv >> 1;               // 0..3  (32-row strip within 128-row half)
    const int wqn = wv & 1;                // 0..1  (64-col strip within 128-col half)

    // XCD-chunked bijective swizzle (r10-proven): 512 blocks = 8 XCDs x (8bn x 8bm)
    const int xc  = blockIdx.x & 7;
    const int idx = blockIdx.x >> 3;
    const int bn  = (xc & 1) * 8 + (idx & 7);    // 0..15
    const int bm  = (xc >> 1) * 8 + (idx >> 3);  // 0..31

    const int8_t* baseA = x + (size_t)bm * BM * IN_F;
    const int8_t* baseB = wq + (size_t)bn * BN * IN_F;

    // staging: T2 swizzle via pre-swizzled global source (rule 21)
    const int seg0 = wv * 2, seg1 = wv * 2 + 1;   // 16 segs x 8 rows per half
    const int r8   = l >> 3;
    const int swc  = (((l & 7) ^ r8) << 4);
    const int8_t* pA0 = baseA + (size_t)(seg0 * 8 + r8) * IN_F + swc;
    const int8_t* pA1 = baseA + (size_t)(seg1 * 8 + r8) * IN_F + swc;
    const int8_t* pB0 = baseB + (size_t)(seg0 * 8 + r8) * IN_F + swc;
    const int8_t* pB1 = baseB + (size_t)(seg1 * 8 + r8) * IN_F + swc;

    // fragment read addressing (32x32 shape): row = base + (l&31), read-XOR key
    const int r32 = l & 31;
    const int kh  = (l >> 5) << 4;         // k-half byte offset (0 / 16)
    const int xk  = (l & 7) << 4;          // row&7 == l&7 (row bases are %8==0)

    int32x16 acc[2][2][2];                 // [MH][NH][cb]
#pragma unroll
    for (int a0i = 0; a0i < 2; ++a0i)
#pragma unroll
        for (int a1i = 0; a1i < 2; ++a1i)
#pragma unroll
            for (int a2i = 0; a2i < 2; ++a2i)
#pragma unroll
                for (int e = 0; e < 16; ++e)
                    acc[a0i][a1i][a2i][e] = 0;

    int32x4 aF[2][4];      // [MH][kb]      32 VGPR
    int32x4 bF[2][2][4];   // [NH][cb][kb]  64 VGPR

    auto stage_half = [&](int h4) {
        const int kt_ = h4 >> 2;
        const int wh_ = h4 & 3;            // 0:A0 1:A1 2:B0 3:B1
        const size_t off = (size_t)(wh_ & 1) * (128 * IN_F) + (size_t)kt_ * BK;
        const int8_t* s0 = ((wh_ < 2) ? pA0 : pB0) + off;
        const int8_t* s1 = ((wh_ < 2) ? pA1 : pB1) + off;
        int8_t* db = ((wh_ < 2) ? lA : lB) + ((kt_ & 1) << 15) + ((wh_ & 1) << 14);
        __builtin_amdgcn_global_load_lds(
            (const AS1 void*)s0, (AS3 void*)(db + seg0 * 1024), 16, 0, 0);
        __builtin_amdgcn_global_load_lds(
            (const AS1 void*)s1, (AS3 void*)(db + seg1 * 1024), 16, 0, 0);
    };

#define LDA_ALL(LABP)                                                                  \
    do {                                                                               \
        _Pragma("unroll") for (int MH = 0; MH < 2; ++MH)                               \
        _Pragma("unroll") for (int kb = 0; kb < 4; ++kb)                               \
            aF[MH][kb] = *(const int32x4*)&(LABP)[(MH << 14) +                         \
                (wqm * 32 + r32) * 128 + (((kb * 32) + kh) ^ xk)];                     \
    } while (0)

#define LDB_ALL(LBBP)                                                                  \
    do {                                                                               \
        _Pragma("unroll") for (int NH = 0; NH < 2; ++NH)                               \
        _Pragma("unroll") for (int cb = 0; cb < 2; ++cb)                               \
        _Pragma("unroll") for (int kb = 0; kb < 4; ++kb)                               \
            bF[NH][cb][kb] = *(const int32x4*)&(LBBP)[(NH << 14) +                     \
                (wqn * 64 + cb * 32 + r32) * 128 + (((kb * 32) + kh) ^ xk)];           \
    } while (0)

#define MMA_ALL()                                                                      \
    do {                                                                               \
        _Pragma("unroll") for (int MH = 0; MH < 2; ++MH)                               \
        _Pragma("unroll") for (int NH = 0; NH < 2; ++NH)                               \
        _Pragma("unroll") for (int cb = 0; cb < 2; ++cb)                               \
        _Pragma("unroll") for (int kb = 0; kb < 4; ++kb)                               \
            acc[MH][NH][cb] = __builtin_amdgcn_mfma_i32_32x32x32_i8(                   \
                aF[MH][kb], bF[NH][cb][kb], acc[MH][NH][cb], 0, 0, 0);                 \
    } while (0)

    // ---- prologue: tile 0 fully staged ----
    stage_half(0); stage_half(1); stage_half(2); stage_half(3);
    asm volatile("s_waitcnt vmcnt(0)" ::: "memory");
    __builtin_amdgcn_s_barrier();

    // ---- main loop: ONE phase per K-tile (r12-verified schedule) ----
    for (int t = 0; t < NT; ++t) {
        const int8_t* lAb = lA + ((t & 1) << 15);
        const int8_t* lBb = lB + ((t & 1) << 15);

        LDA_ALL(lAb); LDB_ALL(lBb);            // 24 ds_read_b128

        if (t + 1 < NT) {                      // full tile t+1 -> other parity
            stage_half(4 * (t + 1) + 0); stage_half(4 * (t + 1) + 1);
            stage_half(4 * (t + 1) + 2); stage_half(4 * (t + 1) + 3);
        }

        __builtin_amdgcn_s_setprio(1);
        MMA_ALL();                             // 32 x 32x32x32 MFMA
        __builtin_amdgcn_s_setprio(0);

        if (t + 1 < NT) asm volatile("s_waitcnt vmcnt(0)" ::: "memory");
        __builtin_amdgcn_s_barrier();
    }

    // ---- epilogue: LDS-staged coalesced float4 nt stores (32-row chunks) ----
    __syncthreads();
    int* eL = (int*)smem;
    const int c4   = tid & 63;          // float4 col index within 256-col block
    const int rowt = tid >> 6;          // 0..7
    const float32x4 sc4 = ((const float32x4*)scale)[bn * 64 + c4];
    const float32x4 bf4 = ((const float32x4*)bias )[bn * 64 + c4];
    const __half bh[4] = { __float2half(bf4[0]), __float2half(bf4[1]),
                           __float2half(bf4[2]), __float2half(bf4[3]) };
    const int rbase = (l >> 5) << 2;    // +4*(lane>>5) term of the C/D row map

    for (int c = 0; c < 8; ++c) {              // 8 chunks of 32 output rows
        if (wqm == (c & 3)) {
            const int MH = c >> 2;
#pragma unroll
            for (int NH = 0; NH < 2; ++NH)
#pragma unroll
                for (int cb = 0; cb < 2; ++cb)
#pragma unroll
                    for (int j = 0; j < 16; ++j) {
                        const int rr = (j & 3) + 8 * (j >> 2) + rbase;
                        eL[rr * ESTR + NH * 128 + wqn * 64 + cb * 32 + r32] =
                            acc[MH][NH][cb][j];
                    }
        }
        __syncthreads();
#pragma unroll
        for (int p = 0; p < 4; ++p) {          // 32 rows, 8 per pass
            const int rl = p * 8 + rowt;
            int32x4 v = *(const int32x4*)&eL[rl * ESTR + c4 * 4];
            float32x4 o;
#pragma unroll
            for (int j = 0; j < 4; ++j) {
                __half h = __float2half((float)v[j] * sc4[j]);
                o[j] = __half2float(__hadd(h, bh[j]));
            }
            const size_t rowg = (size_t)(bm * 256 + c * 32 + rl);
            __builtin_nontemporal_store(o, (float32x4*)out + rowg * (OUT_F / 4) + bn * 64 + c4);
        }
        __syncthreads();   // copy-out done before next chunk overwrites
    }
#undef LDA_ALL
#undef LDB_ALL
#undef MMA_ALL
}

extern "C" void kernel_launch(void* const* d_in, const int* in_sizes, int n_in,
                              void* d_out, int out_size, void* d_ws, size_t ws_size,
                              hipStream_t stream)
{
    const int*   x32   = (const int*)d_in[0];
    const int*   w32   = (const int*)d_in[1];
    const float* scale = (const float*)d_in[2];
    const float* bias  = (const float*)d_in[3];
    float* out = (float*)d_out;

    int8_t* x8 = (int8_t*)d_ws;
    int8_t* w8 = x8 + (size_t)TOKENS * IN_F;

    pack_all_kernel<<<3072, 256, 0, stream>>>(x32, w32, bias, (uint32_t*)x8, (uint32_t*)w8,
                                              out + (size_t)TOKENS * OUT_F);

    w8a8_gemm_kernel<<<512, 512, 0, stream>>>(x8, w8, scale, bias, out);
}